// Round 5
// baseline (364.204 us; speedup 1.0000x reference)
//
#include <hip/hip_runtime.h>
#include <hip/hip_bf16.h>

#define N_NODES 32768
#define N_EDGES 524288
#define B_GRAPHS 512

typedef __attribute__((ext_vector_type(8))) short sh8;    // 8 bf16 (4 VGPR) MFMA operand
typedef __attribute__((ext_vector_type(4))) float f32x4;  // MFMA accumulator

// ---------------- bf16 helpers ----------------
__device__ __forceinline__ unsigned short f2b(float f) {
    unsigned int u = __float_as_uint(f);
    return (unsigned short)((u + 0x7FFFu + ((u >> 16) & 1u)) >> 16);
}
__device__ __forceinline__ float blo(unsigned int u) { return __uint_as_float(u << 16); }
__device__ __forceinline__ float bhi(unsigned int u) { return __uint_as_float(u & 0xFFFF0000u); }
__device__ __forceinline__ float gelu_exact(float z) {
    return 0.5f * z * (1.0f + erff(z * 0.70710678118654752440f));
}

// ---------------- weight prep: transpose + fp32->bf16 (+ deg zero) ----------------
__global__ __launch_bounds__(256) void k_prep(const float* __restrict__ W1,
                                              const float* __restrict__ W2,
                                              const float* __restrict__ gW1,
                                              unsigned short* __restrict__ W1T,
                                              unsigned short* __restrict__ W2T,
                                              unsigned short* __restrict__ gW1T,
                                              int* __restrict__ deg) {
    int tid = blockIdx.x * 256 + threadIdx.x;   // 7*32768 total
    if (tid < N_NODES) deg[tid] = 0;            // fold k_zero in (k_deg runs after, same stream)
    int m = tid >> 15, i = tid & 32767;
    if (m < 3) {
        int r = i >> 8, c = i & 255;
        W1T[m * 32768 + c * 128 + r] = f2b(W1[m * 32768 + i]);
    } else if (m < 6) {
        int mm = m - 3;
        int r = i >> 7, c = i & 127;
        W2T[mm * 32768 + c * 256 + r] = f2b(W2[mm * 32768 + i]);
    } else {
        int r = i >> 8, c = i & 255;
        gW1T[c * 128 + r] = f2b(gW1[i]);
    }
}

// ---------------- CSR build ----------------
__global__ void k_deg(const int* __restrict__ dst, int* __restrict__ deg) {
    int e = blockIdx.x * blockDim.x + threadIdx.x;
    if (e < N_EDGES) atomicAdd(&deg[dst[e]], 1);
}

__global__ __launch_bounds__(1024) void k_scan(const int* __restrict__ deg,
                                               int* __restrict__ offs,
                                               int* __restrict__ cursor) {
    int tid = threadIdx.x;
    int lane = tid & 63, wid = tid >> 6;
    int base = tid * 32;
    int pref[32];
    int run = 0;
    #pragma unroll
    for (int i = 0; i < 32; i++) { pref[i] = run; run += deg[base + i]; }
    int s = run;
    for (int m = 1; m < 64; m <<= 1) { int t = __shfl_up(s, m); if (lane >= m) s += t; }
    __shared__ int wsum[16];
    if (lane == 63) wsum[wid] = s;
    __syncthreads();
    if (tid < 16) {
        int v = wsum[tid];
        for (int m = 1; m < 16; m <<= 1) { int t = __shfl_up(v, m, 16); if (tid >= m) v += t; }
        wsum[tid] = v;
    }
    __syncthreads();
    int wbase = wid ? wsum[wid - 1] : 0;
    int ebase = wbase + (s - run);
    #pragma unroll
    for (int i = 0; i < 32; i++) {
        int o = ebase + pref[i];
        offs[base + i] = o;
        cursor[base + i] = o;
    }
    if (tid == 1023) offs[N_NODES] = ebase + run;
}

__global__ void k_scatter(const int* __restrict__ src, const int* __restrict__ dst,
                          const int* __restrict__ attr, int* __restrict__ cursor,
                          int* __restrict__ csr) {
    int e = blockIdx.x * blockDim.x + threadIdx.x;
    if (e < N_EDGES) {
        int p = atomicAdd(&cursor[dst[e]], 1);
        csr[p] = src[e] | (attr[e] << 16);
    }
}

// ---------------- x init: masked gather + atom embedding ----------------
__global__ void k_build_x(const float* __restrict__ logits, const int* __restrict__ feat,
                          const float* __restrict__ aemb, float* __restrict__ x,
                          unsigned short* __restrict__ xb) {
    int idx = blockIdx.x * blockDim.x + threadIdx.x;   // float4 id
    int n = idx >> 5, c = idx & 31;
    int srow = ((n >> 6) << 7) + (n & 63);             // analytic nonzero(mask) index
    float4 lv = ((const float4*)logits)[srow * 32 + c];
    float4 av = ((const float4*)aemb)[feat[n] * 32 + c];
    float4 o;
    o.x = lv.x + av.x; o.y = lv.y + av.y; o.z = lv.z + av.z; o.w = lv.w + av.w;
    ((float4*)x)[idx] = o;
    ushort4 ob;
    ob.x = f2b(o.x); ob.y = f2b(o.y); ob.z = f2b(o.z); ob.w = f2b(o.w);
    ((ushort4*)xb)[idx] = ob;
}

// ---------------- per-node aggregation: half-wave uint2 gathers, 8 edges in flight ----------------
__global__ __launch_bounds__(256) void k_agg(const unsigned short* __restrict__ xb,
                                             const int* __restrict__ offs,
                                             const int* __restrict__ csr,
                                             const float* __restrict__ eemb,
                                             unsigned short* __restrict__ aggb) {
    __shared__ float semb[8 * 128];
    int tid = threadIdx.x;
    for (int i = tid; i < 1024; i += 256) semb[i] = eemb[i];
    __syncthreads();
    int node = blockIdx.x * 4 + (tid >> 6);
    int lane = tid & 63;
    int li = lane & 31, h = lane >> 5;   // half-wave: h=0 even edges, h=1 odd edges
    int o0 = offs[node], o1 = offs[node + 1];
    float a0 = 0.f, a1 = 0.f, a2 = 0.f, a3 = 0.f;
    int e = o0 + h;
    for (; e + 6 < o1; e += 8) {          // 4 edges per half = 8 in flight per wave
        int p0 = csr[e], p1 = csr[e + 2], p2 = csr[e + 4], p3 = csr[e + 6];
        uint2 u0 = *(const uint2*)(xb + (size_t)(p0 & 0xFFFF) * 128 + li * 4);
        uint2 u1 = *(const uint2*)(xb + (size_t)(p1 & 0xFFFF) * 128 + li * 4);
        uint2 u2 = *(const uint2*)(xb + (size_t)(p2 & 0xFFFF) * 128 + li * 4);
        uint2 u3 = *(const uint2*)(xb + (size_t)(p3 & 0xFFFF) * 128 + li * 4);
        float4 e0 = *(const float4*)&semb[(p0 >> 16) * 128 + li * 4];
        float4 e1 = *(const float4*)&semb[(p1 >> 16) * 128 + li * 4];
        float4 e2 = *(const float4*)&semb[(p2 >> 16) * 128 + li * 4];
        float4 e3 = *(const float4*)&semb[(p3 >> 16) * 128 + li * 4];
        a0 += fmaxf(blo(u0.x) + e0.x, 0.f); a1 += fmaxf(bhi(u0.x) + e0.y, 0.f);
        a2 += fmaxf(blo(u0.y) + e0.z, 0.f); a3 += fmaxf(bhi(u0.y) + e0.w, 0.f);
        a0 += fmaxf(blo(u1.x) + e1.x, 0.f); a1 += fmaxf(bhi(u1.x) + e1.y, 0.f);
        a2 += fmaxf(blo(u1.y) + e1.z, 0.f); a3 += fmaxf(bhi(u1.y) + e1.w, 0.f);
        a0 += fmaxf(blo(u2.x) + e2.x, 0.f); a1 += fmaxf(bhi(u2.x) + e2.y, 0.f);
        a2 += fmaxf(blo(u2.y) + e2.z, 0.f); a3 += fmaxf(bhi(u2.y) + e2.w, 0.f);
        a0 += fmaxf(blo(u3.x) + e3.x, 0.f); a1 += fmaxf(bhi(u3.x) + e3.y, 0.f);
        a2 += fmaxf(blo(u3.y) + e3.z, 0.f); a3 += fmaxf(bhi(u3.y) + e3.w, 0.f);
    }
    for (; e < o1; e += 2) {
        int pk = csr[e];
        uint2 u = *(const uint2*)(xb + (size_t)(pk & 0xFFFF) * 128 + li * 4);
        float4 ev = *(const float4*)&semb[(pk >> 16) * 128 + li * 4];
        a0 += fmaxf(blo(u.x) + ev.x, 0.f); a1 += fmaxf(bhi(u.x) + ev.y, 0.f);
        a2 += fmaxf(blo(u.y) + ev.z, 0.f); a3 += fmaxf(bhi(u.y) + ev.w, 0.f);
    }
    a0 += __shfl_xor(a0, 32); a1 += __shfl_xor(a1, 32);
    a2 += __shfl_xor(a2, 32); a3 += __shfl_xor(a3, 32);
    if (h == 0) {
        uint2 wv;
        wv.x = (unsigned int)f2b(a0) | ((unsigned int)f2b(a1) << 16);
        wv.y = (unsigned int)f2b(a2) | ((unsigned int)f2b(a3) << 16);
        *(uint2*)(aggb + (size_t)node * 128 + li * 4) = wv;
    }
}

// ---------------- fused GNN layer: x += LN(relu(agg@W1+b1)@W2+b2) ----------------
// BM=64 per block, 256 thr = 4 waves, grid 512 (2 blocks/CU resident; 4/CU capacity at
// 33.8 KB LDS). Wave w owns rows w*16..+16. Phase1: T = relu(agg@W1+b1) in LDS (bf16),
// N=256 done in 2 col-halves of 128 (acc[8] at a time; A fragments preloaded once).
// Phase2: H = T@W2+b2, LN over the 128 cols, x += LN. W fragments stream from L2
// (shared by all blocks). No __launch_bounds__ min-occupancy: round-4's (512,4)
// pinched VGPR to 64 and spilled to L2-resident scratch (48us/dispatch, MfmaUtil 3%).
__global__ __launch_bounds__(256) void k_layer(const unsigned short* __restrict__ A,
                                               const unsigned short* __restrict__ W1T,
                                               const float* __restrict__ b1,
                                               const unsigned short* __restrict__ W2T,
                                               const float* __restrict__ b2,
                                               const float* __restrict__ lng,
                                               const float* __restrict__ lnb,
                                               float* __restrict__ x,
                                               unsigned short* __restrict__ xb) {
    __shared__ __align__(16) unsigned short T[64][264];   // 33.8 KB
    int tid = threadIdx.x;
    int row0 = blockIdx.x * 64;
    int l = tid & 63, w = tid >> 6;
    int fr = l & 15, hi = l >> 4, fk = hi * 8;
    // preload this wave's A fragments (16 rows x K=128), reused for both col halves
    sh8 afr[4];
    #pragma unroll
    for (int kc = 0; kc < 4; kc++)
        afr[kc] = *(const sh8*)(A + (size_t)(row0 + w * 16 + fr) * 128 + kc * 32 + fk);
    // ---- phase 1 ----
    #pragma unroll
    for (int ch = 0; ch < 2; ch++) {
        f32x4 acc[8];
        #pragma unroll
        for (int c = 0; c < 8; c++) acc[c] = (f32x4){0.f, 0.f, 0.f, 0.f};
        #pragma unroll
        for (int kc = 0; kc < 4; kc++) {
            #pragma unroll
            for (int c = 0; c < 8; c++) {
                sh8 b = *(const sh8*)(W1T + (size_t)(ch * 128 + c * 16 + fr) * 128 + kc * 32 + fk);
                acc[c] = __builtin_amdgcn_mfma_f32_16x16x32_bf16(afr[kc], b, acc[c], 0, 0, 0);
            }
        }
        int rb = w * 16 + hi * 4;
        #pragma unroll
        for (int c = 0; c < 8; c++) {
            int col = ch * 128 + c * 16 + fr;
            float bv = b1[col];
            #pragma unroll
            for (int q = 0; q < 4; q++)
                T[rb + q][col] = f2b(fmaxf(acc[c][q] + bv, 0.f));
        }
    }
    __syncthreads();
    // ---- phase 2: rows w*16..+16, K=256, N=128 ----
    f32x4 acc[8];
    #pragma unroll
    for (int c = 0; c < 8; c++) acc[c] = (f32x4){0.f, 0.f, 0.f, 0.f};
    #pragma unroll 2
    for (int kc = 0; kc < 8; kc++) {
        sh8 a = *(const sh8*)&T[w * 16 + fr][kc * 32 + fk];
        #pragma unroll
        for (int c = 0; c < 8; c++) {
            sh8 b = *(const sh8*)(W2T + (size_t)(c * 16 + fr) * 256 + kc * 32 + fk);
            acc[c] = __builtin_amdgcn_mfma_f32_16x16x32_bf16(a, b, acc[c], 0, 0, 0);
        }
    }
    // epilogue: bias folded in-place, LN over 128 cols, x += LN (fp32 master + bf16 shadow)
    float s0 = 0.f, s1 = 0.f, s2 = 0.f, s3 = 0.f;
    float q0 = 0.f, q1 = 0.f, q2 = 0.f, q3 = 0.f;
    #pragma unroll
    for (int c = 0; c < 8; c++) {
        float bv = b2[c * 16 + fr];
        #pragma unroll
        for (int q = 0; q < 4; q++) acc[c][q] += bv;
        s0 += acc[c][0]; q0 += acc[c][0] * acc[c][0];
        s1 += acc[c][1]; q1 += acc[c][1] * acc[c][1];
        s2 += acc[c][2]; q2 += acc[c][2] * acc[c][2];
        s3 += acc[c][3]; q3 += acc[c][3] * acc[c][3];
    }
    #pragma unroll
    for (int m = 1; m < 16; m <<= 1) {
        s0 += __shfl_xor(s0, m); q0 += __shfl_xor(q0, m);
        s1 += __shfl_xor(s1, m); q1 += __shfl_xor(q1, m);
        s2 += __shfl_xor(s2, m); q2 += __shfl_xor(q2, m);
        s3 += __shfl_xor(s3, m); q3 += __shfl_xor(q3, m);
    }
    float mu[4], rs_[4];
    mu[0] = s0 * (1.f / 128.f); rs_[0] = rsqrtf(q0 * (1.f / 128.f) - mu[0] * mu[0] + 1e-5f);
    mu[1] = s1 * (1.f / 128.f); rs_[1] = rsqrtf(q1 * (1.f / 128.f) - mu[1] * mu[1] + 1e-5f);
    mu[2] = s2 * (1.f / 128.f); rs_[2] = rsqrtf(q2 * (1.f / 128.f) - mu[2] * mu[2] + 1e-5f);
    mu[3] = s3 * (1.f / 128.f); rs_[3] = rsqrtf(q3 * (1.f / 128.f) - mu[3] * mu[3] + 1e-5f);
    int rbase = row0 + w * 16 + hi * 4;
    #pragma unroll
    for (int c = 0; c < 8; c++) {
        int col = c * 16 + fr;
        float g = lng[col], bb = lnb[col];
        #pragma unroll
        for (int q = 0; q < 4; q++) {
            size_t idx = (size_t)(rbase + q) * 128 + col;
            float nx = x[idx] + (acc[c][q] - mu[q]) * rs_[q] * g + bb;
            x[idx] = nx;
            xb[idx] = f2b(nx);
        }
    }
}

// ---------------- fused gate: gate = relu(LN(x@gW1+b1))·w2 + b2 ----------------
// Same BM=64 / 4-wave phase-1 as k_layer (no relu into T); phase-2: LN(256)->relu->dot.
__global__ __launch_bounds__(256) void k_gatef(const unsigned short* __restrict__ xbin,
                                               const unsigned short* __restrict__ gW1T,
                                               const float* __restrict__ b1,
                                               const float* __restrict__ lng,
                                               const float* __restrict__ lnb,
                                               const float* __restrict__ w2,
                                               const float* __restrict__ b2,
                                               float* __restrict__ gate) {
    __shared__ __align__(16) unsigned short T[64][264];
    int tid = threadIdx.x;
    int row0 = blockIdx.x * 64;
    int l = tid & 63, w = tid >> 6;
    int fr = l & 15, hi = l >> 4, fk = hi * 8;
    sh8 afr[4];
    #pragma unroll
    for (int kc = 0; kc < 4; kc++)
        afr[kc] = *(const sh8*)(xbin + (size_t)(row0 + w * 16 + fr) * 128 + kc * 32 + fk);
    #pragma unroll
    for (int ch = 0; ch < 2; ch++) {
        f32x4 acc[8];
        #pragma unroll
        for (int c = 0; c < 8; c++) acc[c] = (f32x4){0.f, 0.f, 0.f, 0.f};
        #pragma unroll
        for (int kc = 0; kc < 4; kc++) {
            #pragma unroll
            for (int c = 0; c < 8; c++) {
                sh8 b = *(const sh8*)(gW1T + (size_t)(ch * 128 + c * 16 + fr) * 128 + kc * 32 + fk);
                acc[c] = __builtin_amdgcn_mfma_f32_16x16x32_bf16(afr[kc], b, acc[c], 0, 0, 0);
            }
        }
        int rb = w * 16 + hi * 4;
        #pragma unroll
        for (int c = 0; c < 8; c++) {
            int col = ch * 128 + c * 16 + fr;
            float bv = b1[col];
            #pragma unroll
            for (int q = 0; q < 4; q++)
                T[rb + q][col] = f2b(acc[c][q] + bv);   // no relu before LN
        }
    }
    __syncthreads();
    // phase 2: LN(256) -> relu -> dot(w2); 4 threads per row, 64 rows
    int row = tid >> 2, qd = tid & 3;
    float s = 0.f, sq = 0.f;
    #pragma unroll 4
    for (int j = 0; j < 16; j++) {
        uint2 u = *(const uint2*)&T[row][qd * 64 + j * 4];
        float v0 = blo(u.x), v1 = bhi(u.x), v2 = blo(u.y), v3 = bhi(u.y);
        s += v0 + v1 + v2 + v3;
        sq += v0 * v0 + v1 * v1 + v2 * v2 + v3 * v3;
    }
    s += __shfl_xor(s, 1); s += __shfl_xor(s, 2);
    sq += __shfl_xor(sq, 1); sq += __shfl_xor(sq, 2);
    float mu = s * (1.f / 256.f);
    float rcp = rsqrtf(sq * (1.f / 256.f) - mu * mu + 1e-5f);
    float acc = 0.f;
    #pragma unroll 4
    for (int j = 0; j < 16; j++) {
        int col = qd * 64 + j * 4;
        uint2 u = *(const uint2*)&T[row][col];
        float4 g4 = *(const float4*)&lng[col];
        float4 e4 = *(const float4*)&lnb[col];
        float4 w4 = *(const float4*)&w2[col];
        acc += fmaxf((blo(u.x) - mu) * rcp * g4.x + e4.x, 0.f) * w4.x;
        acc += fmaxf((bhi(u.x) - mu) * rcp * g4.y + e4.y, 0.f) * w4.y;
        acc += fmaxf((blo(u.y) - mu) * rcp * g4.z + e4.z, 0.f) * w4.z;
        acc += fmaxf((bhi(u.y) - mu) * rcp * g4.w + e4.w, 0.f) * w4.w;
    }
    acc += __shfl_xor(acc, 1); acc += __shfl_xor(acc, 2);
    if (qd == 0) gate[row0 + row] = acc + b2[0];
}

// ---------------- attention pooling per graph (fp32 x) ----------------
__global__ __launch_bounds__(256) void k_pool(const float* __restrict__ x,
                                              const float* __restrict__ gate,
                                              float* __restrict__ g) {
    __shared__ float sw[64];
    __shared__ float sacc[128];
    int b = blockIdx.x, tid = threadIdx.x;
    if (tid < 64) {
        float gv = gate[b * 64 + tid];
        float m = gv;
        #pragma unroll
        for (int mk = 1; mk < 64; mk <<= 1) m = fmaxf(m, __shfl_xor(m, mk));
        float e = expf(gv - m);
        float s = e;
        #pragma unroll
        for (int mk = 1; mk < 64; mk <<= 1) s += __shfl_xor(s, mk);
        sw[tid] = e / s;
    }
    __syncthreads();
    int d = tid & 127, h = tid >> 7;
    float acc = 0.f;
    for (int i = h * 32; i < h * 32 + 32; i++)
        acc += sw[i] * x[(size_t)(b * 64 + i) * 128 + d];
    if (h == 0) sacc[d] = acc;
    __syncthreads();
    if (h == 1) g[b * 128 + d] = sacc[d] + acc;
}

// ---------------- residual blocks + head, one block per graph (fp32) ----------------
__global__ __launch_bounds__(128) void k_tail(const float* __restrict__ g_in,
        const float* __restrict__ fc1W, const float* __restrict__ fc1b,
        const float* __restrict__ ln1g, const float* __restrict__ ln1b,
        const float* __restrict__ fc2W, const float* __restrict__ fc2b,
        const float* __restrict__ ln2g, const float* __restrict__ ln2b,
        const float* __restrict__ pW1, const float* __restrict__ pb1,
        const float* __restrict__ pW2, const float* __restrict__ pb2,
        float* __restrict__ out) {
    __shared__ float sg[128], sh[128];
    __shared__ float ps[2], pq[2];
    int b = blockIdx.x, tid = threadIdx.x;
    int w = tid >> 6;
    sg[tid] = g_in[b * 128 + tid];
    __syncthreads();
    for (int r = 0; r < 2; r++) {
        const float* W1 = fc1W + r * 16384;
        float acc = fc1b[r * 128 + tid];
        for (int k = 0; k < 128; k++) acc += sg[k] * W1[k * 128 + tid];
        float s = acc, q = acc * acc;
        #pragma unroll
        for (int m = 1; m < 64; m <<= 1) { s += __shfl_xor(s, m); q += __shfl_xor(q, m); }
        __syncthreads();
        if ((tid & 63) == 0) { ps[w] = s; pq[w] = q; }
        __syncthreads();
        float S = ps[0] + ps[1], Q = pq[0] + pq[1];
        float mu = S * (1.f / 128.f);
        float var = Q * (1.f / 128.f) - mu * mu;
        float z = (acc - mu) * rsqrtf(var + 1e-5f) * ln1g[r * 128 + tid] + ln1b[r * 128 + tid];
        z = gelu_exact(z);
        __syncthreads();
        sh[tid] = z;
        __syncthreads();
        const float* W2 = fc2W + r * 16384;
        float acc2 = fc2b[r * 128 + tid];
        for (int k = 0; k < 128; k++) acc2 += sh[k] * W2[k * 128 + tid];
        s = acc2; q = acc2 * acc2;
        #pragma unroll
        for (int m = 1; m < 64; m <<= 1) { s += __shfl_xor(s, m); q += __shfl_xor(q, m); }
        __syncthreads();
        if ((tid & 63) == 0) { ps[w] = s; pq[w] = q; }
        __syncthreads();
        S = ps[0] + ps[1]; Q = pq[0] + pq[1];
        mu = S * (1.f / 128.f);
        var = Q * (1.f / 128.f) - mu * mu;
        float z2 = (acc2 - mu) * rsqrtf(var + 1e-5f) * ln2g[r * 128 + tid] + ln2b[r * 128 + tid];
        __syncthreads();
        sg[tid] = sg[tid] + z2;
        __syncthreads();
    }
    float acc = pb1[tid];
    for (int k = 0; k < 128; k++) acc += sg[k] * pW1[k * 128 + tid];
    __syncthreads();
    sh[tid] = gelu_exact(acc);
    __syncthreads();
    if (tid < 12) {
        float o = pb2[tid];
        for (int k = 0; k < 128; k++) o += sh[k] * pW2[k * 12 + tid];
        out[b * 12 + tid] = o;
    }
}

// ---------------- launch ----------------
extern "C" void kernel_launch(void* const* d_in, const int* in_sizes, int n_in,
                              void* d_out, int out_size, void* d_ws, size_t ws_size,
                              hipStream_t stream) {
    const float* logits    = (const float*)d_in[0];
    const int*   atom_feat = (const int*)d_in[2];
    const int*   edge_src  = (const int*)d_in[3];
    const int*   edge_dst  = edge_src + N_EDGES;
    const int*   edge_attr = (const int*)d_in[4];
    const float* atom_emb  = (const float*)d_in[6];
    const float* edge_emb  = (const float*)d_in[7];
    const float* gnn_W1    = (const float*)d_in[8];
    const float* gnn_b1    = (const float*)d_in[9];
    const float* gnn_W2    = (const float*)d_in[10];
    const float* gnn_b2    = (const float*)d_in[11];
    const float* gnn_ln_g  = (const float*)d_in[12];
    const float* gnn_ln_b  = (const float*)d_in[13];
    const float* gate_W1   = (const float*)d_in[14];
    const float* gate_b1   = (const float*)d_in[15];
    const float* gate_ln_g = (const float*)d_in[16];
    const float* gate_ln_b = (const float*)d_in[17];
    const float* gate_W2   = (const float*)d_in[18];
    const float* gate_b2   = (const float*)d_in[19];
    const float* res_fc1_W = (const float*)d_in[20];
    const float* res_fc1_b = (const float*)d_in[21];
    const float* res_ln1_g = (const float*)d_in[22];
    const float* res_ln1_b = (const float*)d_in[23];
    const float* res_fc2_W = (const float*)d_in[24];
    const float* res_fc2_b = (const float*)d_in[25];
    const float* res_ln2_g = (const float*)d_in[26];
    const float* res_ln2_b = (const float*)d_in[27];
    const float* pred_W1   = (const float*)d_in[28];
    const float* pred_b1   = (const float*)d_in[29];
    const float* pred_W2   = (const float*)d_in[30];
    const float* pred_b2   = (const float*)d_in[31];
    float* out = (float*)d_out;

    char* w = (char*)d_ws;
    float*          x    = (float*)w;          w += (size_t)N_NODES * 128 * 4;  // 16 MB fp32 master
    unsigned short* xb   = (unsigned short*)w; w += (size_t)N_NODES * 128 * 2;  // 8 MB bf16 shadow
    unsigned short* aggb = (unsigned short*)w; w += (size_t)N_NODES * 128 * 2;  // 8 MB
    unsigned short* W1T  = (unsigned short*)w; w += 3 * 32768 * 2;
    unsigned short* W2T  = (unsigned short*)w; w += 3 * 32768 * 2;
    unsigned short* gW1T = (unsigned short*)w; w += 32768 * 2;
    int*   deg    = (int*)w;   w += N_NODES * 4;
    int*   offs   = (int*)w;   w += (N_NODES + 64) * 4;
    int*   cursor = (int*)w;   w += N_NODES * 4;
    int*   csr    = (int*)w;   w += N_EDGES * 4;
    float* gate   = (float*)w; w += N_NODES * 4;
    float* gpool  = (float*)w; w += B_GRAPHS * 128 * 4;

    // weight prep (+deg zero) + CSR build
    k_prep<<<7 * 32768 / 256, 256, 0, stream>>>(gnn_W1, gnn_W2, gate_W1, W1T, W2T, gW1T, deg);
    k_deg<<<N_EDGES / 256, 256, 0, stream>>>(edge_dst, deg);
    k_scan<<<1, 1024, 0, stream>>>(deg, offs, cursor);
    k_scatter<<<N_EDGES / 256, 256, 0, stream>>>(edge_src, edge_dst, edge_attr, cursor, csr);

    // x = logits[mask] + atom_emb[feat]
    k_build_x<<<N_NODES * 32 / 256, 256, 0, stream>>>(logits, atom_feat, atom_emb, x, xb);

    // 3 GNN layers: aggregate, then fused GEMM1+GEMM2+LN+residual
    for (int l = 0; l < 3; l++) {
        k_agg<<<N_NODES / 4, 256, 0, stream>>>(xb, offs, csr, edge_emb, aggb);
        k_layer<<<N_NODES / 64, 256, 0, stream>>>(
            aggb, W1T + l * 32768, gnn_b1 + l * 256,
            W2T + l * 32768, gnn_b2 + l * 128,
            gnn_ln_g + l * 128, gnn_ln_b + l * 128, x, xb);
    }

    // fused gate
    k_gatef<<<N_NODES / 64, 256, 0, stream>>>(
        xb, gW1T, gate_b1, gate_ln_g, gate_ln_b, gate_W2, gate_b2, gate);

    // attention pooling
    k_pool<<<B_GRAPHS, 256, 0, stream>>>(x, gate, gpool);

    // residual blocks + head
    k_tail<<<B_GRAPHS, 128, 0, stream>>>(gpool,
        res_fc1_W, res_fc1_b, res_ln1_g, res_ln1_b,
        res_fc2_W, res_fc2_b, res_ln2_g, res_ln2_b,
        pred_W1, pred_b1, pred_W2, pred_b2, out);
}

// Round 6
// 281.304 us; speedup vs baseline: 1.2947x; 1.2947x over previous
//
#include <hip/hip_runtime.h>
#include <hip/hip_bf16.h>

#define N_NODES 32768
#define N_EDGES 524288
#define B_GRAPHS 512

typedef __attribute__((ext_vector_type(8))) short sh8;    // 8 bf16 (4 VGPR) MFMA operand
typedef __attribute__((ext_vector_type(4))) float f32x4;  // MFMA accumulator

// ---------------- bf16 helpers ----------------
__device__ __forceinline__ unsigned short f2b(float f) {
    unsigned int u = __float_as_uint(f);
    return (unsigned short)((u + 0x7FFFu + ((u >> 16) & 1u)) >> 16);
}
__device__ __forceinline__ float blo(unsigned int u) { return __uint_as_float(u << 16); }
__device__ __forceinline__ float bhi(unsigned int u) { return __uint_as_float(u & 0xFFFF0000u); }
__device__ __forceinline__ float gelu_exact(float z) {
    return 0.5f * z * (1.0f + erff(z * 0.70710678118654752440f));
}

// ---------------- weight prep: transpose + fp32->bf16 (+ deg zero) ----------------
__global__ __launch_bounds__(256) void k_prep(const float* __restrict__ W1,
                                              const float* __restrict__ W2,
                                              const float* __restrict__ gW1,
                                              unsigned short* __restrict__ W1T,
                                              unsigned short* __restrict__ W2T,
                                              unsigned short* __restrict__ gW1T,
                                              int* __restrict__ deg) {
    int tid = blockIdx.x * 256 + threadIdx.x;   // 7*32768 total
    if (tid < N_NODES) deg[tid] = 0;            // fold k_zero in (k_deg runs after, same stream)
    int m = tid >> 15, i = tid & 32767;
    if (m < 3) {
        int r = i >> 8, c = i & 255;
        W1T[m * 32768 + c * 128 + r] = f2b(W1[m * 32768 + i]);   // [n=256][k=128]
    } else if (m < 6) {
        int mm = m - 3;
        int r = i >> 7, c = i & 127;
        W2T[mm * 32768 + c * 256 + r] = f2b(W2[mm * 32768 + i]); // [n=128][k=256]
    } else {
        int r = i >> 8, c = i & 255;
        gW1T[c * 128 + r] = f2b(gW1[i]);                         // [n=256][k=128]
    }
}

// ---------------- CSR build ----------------
__global__ void k_deg(const int* __restrict__ dst, int* __restrict__ deg) {
    int e = blockIdx.x * blockDim.x + threadIdx.x;
    if (e < N_EDGES) atomicAdd(&deg[dst[e]], 1);
}

__global__ __launch_bounds__(1024) void k_scan(const int* __restrict__ deg,
                                               int* __restrict__ offs,
                                               int* __restrict__ cursor) {
    int tid = threadIdx.x;
    int lane = tid & 63, wid = tid >> 6;
    int base = tid * 32;
    int pref[32];
    int run = 0;
    #pragma unroll
    for (int i = 0; i < 32; i++) { pref[i] = run; run += deg[base + i]; }
    int s = run;
    for (int m = 1; m < 64; m <<= 1) { int t = __shfl_up(s, m); if (lane >= m) s += t; }
    __shared__ int wsum[16];
    if (lane == 63) wsum[wid] = s;
    __syncthreads();
    if (tid < 16) {
        int v = wsum[tid];
        for (int m = 1; m < 16; m <<= 1) { int t = __shfl_up(v, m, 16); if (tid >= m) v += t; }
        wsum[tid] = v;
    }
    __syncthreads();
    int wbase = wid ? wsum[wid - 1] : 0;
    int ebase = wbase + (s - run);
    #pragma unroll
    for (int i = 0; i < 32; i++) {
        int o = ebase + pref[i];
        offs[base + i] = o;
        cursor[base + i] = o;
    }
    if (tid == 1023) offs[N_NODES] = ebase + run;
}

__global__ void k_scatter(const int* __restrict__ src, const int* __restrict__ dst,
                          const int* __restrict__ attr, int* __restrict__ cursor,
                          int* __restrict__ csr) {
    int e = blockIdx.x * blockDim.x + threadIdx.x;
    if (e < N_EDGES) {
        int p = atomicAdd(&cursor[dst[e]], 1);
        csr[p] = src[e] | (attr[e] << 16);
    }
}

// ---------------- x init: masked gather + atom embedding ----------------
__global__ void k_build_x(const float* __restrict__ logits, const int* __restrict__ feat,
                          const float* __restrict__ aemb, float* __restrict__ x,
                          unsigned short* __restrict__ xb) {
    int idx = blockIdx.x * blockDim.x + threadIdx.x;   // float4 id
    int n = idx >> 5, c = idx & 31;
    int srow = ((n >> 6) << 7) + (n & 63);             // analytic nonzero(mask) index
    float4 lv = ((const float4*)logits)[srow * 32 + c];
    float4 av = ((const float4*)aemb)[feat[n] * 32 + c];
    float4 o;
    o.x = lv.x + av.x; o.y = lv.y + av.y; o.z = lv.z + av.z; o.w = lv.w + av.w;
    ((float4*)x)[idx] = o;
    ushort4 ob;
    ob.x = f2b(o.x); ob.y = f2b(o.y); ob.z = f2b(o.z); ob.w = f2b(o.w);
    ((ushort4*)xb)[idx] = ob;
}

// ---------------- per-node aggregation: half-wave uint2 gathers, 16 edges in flight ----------------
__global__ __launch_bounds__(256) void k_agg(const unsigned short* __restrict__ xb,
                                             const int* __restrict__ offs,
                                             const int* __restrict__ csr,
                                             const float* __restrict__ eemb,
                                             unsigned short* __restrict__ aggb) {
    __shared__ float semb[8 * 128];
    int tid = threadIdx.x;
    for (int i = tid; i < 1024; i += 256) semb[i] = eemb[i];
    __syncthreads();
    int node = blockIdx.x * 4 + (tid >> 6);
    int lane = tid & 63;
    int li = lane & 31, h = lane >> 5;   // half-wave: h=0 even edges, h=1 odd edges
    int o0 = offs[node], o1 = offs[node + 1];
    float a0 = 0.f, a1 = 0.f, a2 = 0.f, a3 = 0.f;
    int e = o0 + h;
    for (; e + 14 < o1; e += 16) {        // 8 edges per half = 16 in flight per wave
        int p[8]; uint2 u[8]; float4 ev[8];
        #pragma unroll
        for (int j = 0; j < 8; j++) p[j] = csr[e + 2 * j];
        #pragma unroll
        for (int j = 0; j < 8; j++)
            u[j] = *(const uint2*)(xb + (size_t)(p[j] & 0xFFFF) * 128 + li * 4);
        #pragma unroll
        for (int j = 0; j < 8; j++)
            ev[j] = *(const float4*)&semb[(p[j] >> 16) * 128 + li * 4];
        #pragma unroll
        for (int j = 0; j < 8; j++) {
            a0 += fmaxf(blo(u[j].x) + ev[j].x, 0.f);
            a1 += fmaxf(bhi(u[j].x) + ev[j].y, 0.f);
            a2 += fmaxf(blo(u[j].y) + ev[j].z, 0.f);
            a3 += fmaxf(bhi(u[j].y) + ev[j].w, 0.f);
        }
    }
    for (; e + 6 < o1; e += 8) {          // 4-wide mid tail
        int p[4]; uint2 u[4]; float4 ev[4];
        #pragma unroll
        for (int j = 0; j < 4; j++) p[j] = csr[e + 2 * j];
        #pragma unroll
        for (int j = 0; j < 4; j++)
            u[j] = *(const uint2*)(xb + (size_t)(p[j] & 0xFFFF) * 128 + li * 4);
        #pragma unroll
        for (int j = 0; j < 4; j++)
            ev[j] = *(const float4*)&semb[(p[j] >> 16) * 128 + li * 4];
        #pragma unroll
        for (int j = 0; j < 4; j++) {
            a0 += fmaxf(blo(u[j].x) + ev[j].x, 0.f);
            a1 += fmaxf(bhi(u[j].x) + ev[j].y, 0.f);
            a2 += fmaxf(blo(u[j].y) + ev[j].z, 0.f);
            a3 += fmaxf(bhi(u[j].y) + ev[j].w, 0.f);
        }
    }
    for (; e < o1; e += 2) {
        int pk = csr[e];
        uint2 u = *(const uint2*)(xb + (size_t)(pk & 0xFFFF) * 128 + li * 4);
        float4 ev = *(const float4*)&semb[(pk >> 16) * 128 + li * 4];
        a0 += fmaxf(blo(u.x) + ev.x, 0.f); a1 += fmaxf(bhi(u.x) + ev.y, 0.f);
        a2 += fmaxf(blo(u.y) + ev.z, 0.f); a3 += fmaxf(bhi(u.y) + ev.w, 0.f);
    }
    a0 += __shfl_xor(a0, 32); a1 += __shfl_xor(a1, 32);
    a2 += __shfl_xor(a2, 32); a3 += __shfl_xor(a3, 32);
    if (h == 0) {
        uint2 wv;
        wv.x = (unsigned int)f2b(a0) | ((unsigned int)f2b(a1) << 16);
        wv.y = (unsigned int)f2b(a2) | ((unsigned int)f2b(a3) << 16);
        *(uint2*)(aggb + (size_t)node * 128 + li * 4) = wv;
    }
}

// ---------------- fused GNN layer: x += LN(relu(agg@W1+b1)@W2+b2) ----------------
// BM=128, 512 thr = 8 waves, grid 256 (1 block/CU; LDS 132 KB).
// Round-5 lesson: streaming W fragments from global inside the MFMA loop = ~200cy L2
// latency per fragment, unhidden (50us, MfmaUtil 3%). Now: stage W in LDS once per
// block (padded rows -> 2-way-or-free bank patterns), MFMA feeds on ds_read_b128.
// WS holds W1T [256][132] for phase 1, then is re-staged with W2T [128][264] for
// phase 2 (same 33792-short footprint). T holds the bf16 intermediate [128][264].
__global__ __launch_bounds__(512) void k_layer(const unsigned short* __restrict__ A,
                                               const unsigned short* __restrict__ W1T,
                                               const float* __restrict__ b1,
                                               const unsigned short* __restrict__ W2T,
                                               const float* __restrict__ b2,
                                               const float* __restrict__ lng,
                                               const float* __restrict__ lnb,
                                               float* __restrict__ x,
                                               unsigned short* __restrict__ xb) {
    __shared__ __align__(16) unsigned short WS[33792];     // 67.6 KB
    __shared__ __align__(16) unsigned short T[128][264];   // 67.6 KB
    int tid = threadIdx.x;
    int row0 = blockIdx.x * 128;
    int l = tid & 63, w = tid >> 6;
    int fr = l & 15, hi = l >> 4, fk = hi * 8;
    // A fragments for this wave's 16 rows (K=128), reused across both col halves
    sh8 afr[4];
    #pragma unroll
    for (int kc = 0; kc < 4; kc++)
        afr[kc] = *(const sh8*)(A + (size_t)(row0 + w * 16 + fr) * 128 + kc * 32 + fk);
    // stage W1T [256 n][128 k] -> WS padded rows of 132
    #pragma unroll
    for (int s = tid; s < 4096; s += 512) {
        int n = s >> 4, k8 = s & 15;
        *(uint4*)&WS[n * 132 + k8 * 8] = *(const uint4*)(W1T + (size_t)n * 128 + k8 * 8);
    }
    __syncthreads();
    // ---- phase 1: T = relu(A @ W1 + b1), N=256 in 2 halves ----
    #pragma unroll
    for (int ch = 0; ch < 2; ch++) {
        f32x4 acc[8];
        #pragma unroll
        for (int c = 0; c < 8; c++) acc[c] = (f32x4){0.f, 0.f, 0.f, 0.f};
        #pragma unroll
        for (int kc = 0; kc < 4; kc++) {
            #pragma unroll
            for (int c = 0; c < 8; c++) {
                sh8 b = *(const sh8*)&WS[(ch * 128 + c * 16 + fr) * 132 + kc * 32 + fk];
                acc[c] = __builtin_amdgcn_mfma_f32_16x16x32_bf16(afr[kc], b, acc[c], 0, 0, 0);
            }
        }
        int rb = w * 16 + hi * 4;
        #pragma unroll
        for (int c = 0; c < 8; c++) {
            int col = ch * 128 + c * 16 + fr;
            float bv = b1[col];
            #pragma unroll
            for (int q = 0; q < 4; q++)
                T[rb + q][col] = f2b(fmaxf(acc[c][q] + bv, 0.f));
        }
    }
    __syncthreads();   // all waves done reading WS (and writing T)
    // stage W2T [128 n][256 k] -> WS padded rows of 264
    #pragma unroll
    for (int s = tid; s < 4096; s += 512) {
        int n = s >> 5, k8 = s & 31;
        *(uint4*)&WS[n * 264 + k8 * 8] = *(const uint4*)(W2T + (size_t)n * 256 + k8 * 8);
    }
    __syncthreads();
    // ---- phase 2: H = T @ W2 + b2 (K=256, N=128), LN, x += LN ----
    f32x4 acc[8];
    #pragma unroll
    for (int c = 0; c < 8; c++) acc[c] = (f32x4){0.f, 0.f, 0.f, 0.f};
    #pragma unroll 2
    for (int kc = 0; kc < 8; kc++) {
        sh8 a = *(const sh8*)&T[w * 16 + fr][kc * 32 + fk];
        #pragma unroll
        for (int c = 0; c < 8; c++) {
            sh8 b = *(const sh8*)&WS[(c * 16 + fr) * 264 + kc * 32 + fk];
            acc[c] = __builtin_amdgcn_mfma_f32_16x16x32_bf16(a, b, acc[c], 0, 0, 0);
        }
    }
    float s0 = 0.f, s1 = 0.f, s2 = 0.f, s3 = 0.f;
    float q0 = 0.f, q1 = 0.f, q2 = 0.f, q3 = 0.f;
    #pragma unroll
    for (int c = 0; c < 8; c++) {
        float bv = b2[c * 16 + fr];
        #pragma unroll
        for (int q = 0; q < 4; q++) acc[c][q] += bv;
        s0 += acc[c][0]; q0 += acc[c][0] * acc[c][0];
        s1 += acc[c][1]; q1 += acc[c][1] * acc[c][1];
        s2 += acc[c][2]; q2 += acc[c][2] * acc[c][2];
        s3 += acc[c][3]; q3 += acc[c][3] * acc[c][3];
    }
    #pragma unroll
    for (int m = 1; m < 16; m <<= 1) {
        s0 += __shfl_xor(s0, m); q0 += __shfl_xor(q0, m);
        s1 += __shfl_xor(s1, m); q1 += __shfl_xor(q1, m);
        s2 += __shfl_xor(s2, m); q2 += __shfl_xor(q2, m);
        s3 += __shfl_xor(s3, m); q3 += __shfl_xor(q3, m);
    }
    float mu[4], rs_[4];
    mu[0] = s0 * (1.f / 128.f); rs_[0] = rsqrtf(q0 * (1.f / 128.f) - mu[0] * mu[0] + 1e-5f);
    mu[1] = s1 * (1.f / 128.f); rs_[1] = rsqrtf(q1 * (1.f / 128.f) - mu[1] * mu[1] + 1e-5f);
    mu[2] = s2 * (1.f / 128.f); rs_[2] = rsqrtf(q2 * (1.f / 128.f) - mu[2] * mu[2] + 1e-5f);
    mu[3] = s3 * (1.f / 128.f); rs_[3] = rsqrtf(q3 * (1.f / 128.f) - mu[3] * mu[3] + 1e-5f);
    int rbase = row0 + w * 16 + hi * 4;
    #pragma unroll
    for (int c = 0; c < 8; c++) {
        int col = c * 16 + fr;
        float g = lng[col], bb = lnb[col];
        #pragma unroll
        for (int q = 0; q < 4; q++) {
            size_t idx = (size_t)(rbase + q) * 128 + col;
            float nx = x[idx] + (acc[c][q] - mu[q]) * rs_[q] * g + bb;
            x[idx] = nx;
            xb[idx] = f2b(nx);
        }
    }
}

// ---------------- fused gate: gate = relu(LN(x@gW1+b1))·w2 + b2 ----------------
// Same LDS-staged phase-1 as k_layer (no relu into T); phase-2: LN(256)->relu->dot.
__global__ __launch_bounds__(512) void k_gatef(const unsigned short* __restrict__ xbin,
                                               const unsigned short* __restrict__ gW1T,
                                               const float* __restrict__ b1,
                                               const float* __restrict__ lng,
                                               const float* __restrict__ lnb,
                                               const float* __restrict__ w2,
                                               const float* __restrict__ b2,
                                               float* __restrict__ gate) {
    __shared__ __align__(16) unsigned short WS[33792];
    __shared__ __align__(16) unsigned short T[128][264];
    int tid = threadIdx.x;
    int row0 = blockIdx.x * 128;
    int l = tid & 63, w = tid >> 6;
    int fr = l & 15, hi = l >> 4, fk = hi * 8;
    sh8 afr[4];
    #pragma unroll
    for (int kc = 0; kc < 4; kc++)
        afr[kc] = *(const sh8*)(xbin + (size_t)(row0 + w * 16 + fr) * 128 + kc * 32 + fk);
    #pragma unroll
    for (int s = tid; s < 4096; s += 512) {
        int n = s >> 4, k8 = s & 15;
        *(uint4*)&WS[n * 132 + k8 * 8] = *(const uint4*)(gW1T + (size_t)n * 128 + k8 * 8);
    }
    __syncthreads();
    #pragma unroll
    for (int ch = 0; ch < 2; ch++) {
        f32x4 acc[8];
        #pragma unroll
        for (int c = 0; c < 8; c++) acc[c] = (f32x4){0.f, 0.f, 0.f, 0.f};
        #pragma unroll
        for (int kc = 0; kc < 4; kc++) {
            #pragma unroll
            for (int c = 0; c < 8; c++) {
                sh8 b = *(const sh8*)&WS[(ch * 128 + c * 16 + fr) * 132 + kc * 32 + fk];
                acc[c] = __builtin_amdgcn_mfma_f32_16x16x32_bf16(afr[kc], b, acc[c], 0, 0, 0);
            }
        }
        int rb = w * 16 + hi * 4;
        #pragma unroll
        for (int c = 0; c < 8; c++) {
            int col = ch * 128 + c * 16 + fr;
            float bv = b1[col];
            #pragma unroll
            for (int q = 0; q < 4; q++)
                T[rb + q][col] = f2b(acc[c][q] + bv);   // no relu before LN
        }
    }
    __syncthreads();
    // phase 2: LN(256) -> relu -> dot(w2); 4 threads per row, 128 rows
    int row = tid >> 2, qd = tid & 3;
    float s = 0.f, sq = 0.f;
    #pragma unroll 4
    for (int j = 0; j < 16; j++) {
        uint2 u = *(const uint2*)&T[row][qd * 64 + j * 4];
        float v0 = blo(u.x), v1 = bhi(u.x), v2 = blo(u.y), v3 = bhi(u.y);
        s += v0 + v1 + v2 + v3;
        sq += v0 * v0 + v1 * v1 + v2 * v2 + v3 * v3;
    }
    s += __shfl_xor(s, 1); s += __shfl_xor(s, 2);
    sq += __shfl_xor(sq, 1); sq += __shfl_xor(sq, 2);
    float mu = s * (1.f / 256.f);
    float rcp = rsqrtf(sq * (1.f / 256.f) - mu * mu + 1e-5f);
    float acc = 0.f;
    #pragma unroll 4
    for (int j = 0; j < 16; j++) {
        int col = qd * 64 + j * 4;
        uint2 u = *(const uint2*)&T[row][col];
        float4 g4 = *(const float4*)&lng[col];
        float4 e4 = *(const float4*)&lnb[col];
        float4 w4 = *(const float4*)&w2[col];
        acc += fmaxf((blo(u.x) - mu) * rcp * g4.x + e4.x, 0.f) * w4.x;
        acc += fmaxf((bhi(u.x) - mu) * rcp * g4.y + e4.y, 0.f) * w4.y;
        acc += fmaxf((blo(u.y) - mu) * rcp * g4.z + e4.z, 0.f) * w4.z;
        acc += fmaxf((bhi(u.y) - mu) * rcp * g4.w + e4.w, 0.f) * w4.w;
    }
    acc += __shfl_xor(acc, 1); acc += __shfl_xor(acc, 2);
    if (qd == 0) gate[row0 + row] = acc + b2[0];
}

// ---------------- attention pooling per graph (fp32 x) ----------------
__global__ __launch_bounds__(256) void k_pool(const float* __restrict__ x,
                                              const float* __restrict__ gate,
                                              float* __restrict__ g) {
    __shared__ float sw[64];
    __shared__ float sacc[128];
    int b = blockIdx.x, tid = threadIdx.x;
    if (tid < 64) {
        float gv = gate[b * 64 + tid];
        float m = gv;
        #pragma unroll
        for (int mk = 1; mk < 64; mk <<= 1) m = fmaxf(m, __shfl_xor(m, mk));
        float e = expf(gv - m);
        float s = e;
        #pragma unroll
        for (int mk = 1; mk < 64; mk <<= 1) s += __shfl_xor(s, mk);
        sw[tid] = e / s;
    }
    __syncthreads();
    int d = tid & 127, h = tid >> 7;
    float acc = 0.f;
    for (int i = h * 32; i < h * 32 + 32; i++)
        acc += sw[i] * x[(size_t)(b * 64 + i) * 128 + d];
    if (h == 0) sacc[d] = acc;
    __syncthreads();
    if (h == 1) g[b * 128 + d] = sacc[d] + acc;
}

// ---------------- residual blocks + head, one block per graph (fp32) ----------------
__global__ __launch_bounds__(128) void k_tail(const float* __restrict__ g_in,
        const float* __restrict__ fc1W, const float* __restrict__ fc1b,
        const float* __restrict__ ln1g, const float* __restrict__ ln1b,
        const float* __restrict__ fc2W, const float* __restrict__ fc2b,
        const float* __restrict__ ln2g, const float* __restrict__ ln2b,
        const float* __restrict__ pW1, const float* __restrict__ pb1,
        const float* __restrict__ pW2, const float* __restrict__ pb2,
        float* __restrict__ out) {
    __shared__ float sg[128], sh[128];
    __shared__ float ps[2], pq[2];
    int b = blockIdx.x, tid = threadIdx.x;
    int w = tid >> 6;
    sg[tid] = g_in[b * 128 + tid];
    __syncthreads();
    for (int r = 0; r < 2; r++) {
        const float* W1 = fc1W + r * 16384;
        float acc = fc1b[r * 128 + tid];
        for (int k = 0; k < 128; k++) acc += sg[k] * W1[k * 128 + tid];
        float s = acc, q = acc * acc;
        #pragma unroll
        for (int m = 1; m < 64; m <<= 1) { s += __shfl_xor(s, m); q += __shfl_xor(q, m); }
        __syncthreads();
        if ((tid & 63) == 0) { ps[w] = s; pq[w] = q; }
        __syncthreads();
        float S = ps[0] + ps[1], Q = pq[0] + pq[1];
        float mu = S * (1.f / 128.f);
        float var = Q * (1.f / 128.f) - mu * mu;
        float z = (acc - mu) * rsqrtf(var + 1e-5f) * ln1g[r * 128 + tid] + ln1b[r * 128 + tid];
        z = gelu_exact(z);
        __syncthreads();
        sh[tid] = z;
        __syncthreads();
        const float* W2 = fc2W + r * 16384;
        float acc2 = fc2b[r * 128 + tid];
        for (int k = 0; k < 128; k++) acc2 += sh[k] * W2[k * 128 + tid];
        s = acc2; q = acc2 * acc2;
        #pragma unroll
        for (int m = 1; m < 64; m <<= 1) { s += __shfl_xor(s, m); q += __shfl_xor(q, m); }
        __syncthreads();
        if ((tid & 63) == 0) { ps[w] = s; pq[w] = q; }
        __syncthreads();
        S = ps[0] + ps[1]; Q = pq[0] + pq[1];
        mu = S * (1.f / 128.f);
        var = Q * (1.f / 128.f) - mu * mu;
        float z2 = (acc2 - mu) * rsqrtf(var + 1e-5f) * ln2g[r * 128 + tid] + ln2b[r * 128 + tid];
        __syncthreads();
        sg[tid] = sg[tid] + z2;
        __syncthreads();
    }
    float acc = pb1[tid];
    for (int k = 0; k < 128; k++) acc += sg[k] * pW1[k * 128 + tid];
    __syncthreads();
    sh[tid] = gelu_exact(acc);
    __syncthreads();
    if (tid < 12) {
        float o = pb2[tid];
        for (int k = 0; k < 128; k++) o += sh[k] * pW2[k * 12 + tid];
        out[b * 12 + tid] = o;
    }
}

// ---------------- launch ----------------
extern "C" void kernel_launch(void* const* d_in, const int* in_sizes, int n_in,
                              void* d_out, int out_size, void* d_ws, size_t ws_size,
                              hipStream_t stream) {
    const float* logits    = (const float*)d_in[0];
    const int*   atom_feat = (const int*)d_in[2];
    const int*   edge_src  = (const int*)d_in[3];
    const int*   edge_dst  = edge_src + N_EDGES;
    const int*   edge_attr = (const int*)d_in[4];
    const float* atom_emb  = (const float*)d_in[6];
    const float* edge_emb  = (const float*)d_in[7];
    const float* gnn_W1    = (const float*)d_in[8];
    const float* gnn_b1    = (const float*)d_in[9];
    const float* gnn_W2    = (const float*)d_in[10];
    const float* gnn_b2    = (const float*)d_in[11];
    const float* gnn_ln_g  = (const float*)d_in[12];
    const float* gnn_ln_b  = (const float*)d_in[13];
    const float* gate_W1   = (const float*)d_in[14];
    const float* gate_b1   = (const float*)d_in[15];
    const float* gate_ln_g = (const float*)d_in[16];
    const float* gate_ln_b = (const float*)d_in[17];
    const float* gate_W2   = (const float*)d_in[18];
    const float* gate_b2   = (const float*)d_in[19];
    const float* res_fc1_W = (const float*)d_in[20];
    const float* res_fc1_b = (const float*)d_in[21];
    const float* res_ln1_g = (const float*)d_in[22];
    const float* res_ln1_b = (const float*)d_in[23];
    const float* res_fc2_W = (const float*)d_in[24];
    const float* res_fc2_b = (const float*)d_in[25];
    const float* res_ln2_g = (const float*)d_in[26];
    const float* res_ln2_b = (const float*)d_in[27];
    const float* pred_W1   = (const float*)d_in[28];
    const float* pred_b1   = (const float*)d_in[29];
    const float* pred_W2   = (const float*)d_in[30];
    const float* pred_b2   = (const float*)d_in[31];
    float* out = (float*)d_out;

    char* w = (char*)d_ws;
    float*          x    = (float*)w;          w += (size_t)N_NODES * 128 * 4;  // 16 MB fp32 master
    unsigned short* xb   = (unsigned short*)w; w += (size_t)N_NODES * 128 * 2;  // 8 MB bf16 shadow
    unsigned short* aggb = (unsigned short*)w; w += (size_t)N_NODES * 128 * 2;  // 8 MB
    unsigned short* W1T  = (unsigned short*)w; w += 3 * 32768 * 2;
    unsigned short* W2T  = (unsigned short*)w; w += 3 * 32768 * 2;
    unsigned short* gW1T = (unsigned short*)w; w += 32768 * 2;
    int*   deg    = (int*)w;   w += N_NODES * 4;
    int*   offs   = (int*)w;   w += (N_NODES + 64) * 4;
    int*   cursor = (int*)w;   w += N_NODES * 4;
    int*   csr    = (int*)w;   w += N_EDGES * 4;
    float* gate   = (float*)w; w += N_NODES * 4;
    float* gpool  = (float*)w; w += B_GRAPHS * 128 * 4;

    // weight prep (+deg zero) + CSR build
    k_prep<<<7 * 32768 / 256, 256, 0, stream>>>(gnn_W1, gnn_W2, gate_W1, W1T, W2T, gW1T, deg);
    k_deg<<<N_EDGES / 256, 256, 0, stream>>>(edge_dst, deg);
    k_scan<<<1, 1024, 0, stream>>>(deg, offs, cursor);
    k_scatter<<<N_EDGES / 256, 256, 0, stream>>>(edge_src, edge_dst, edge_attr, cursor, csr);

    // x = logits[mask] + atom_emb[feat]
    k_build_x<<<N_NODES * 32 / 256, 256, 0, stream>>>(logits, atom_feat, atom_emb, x, xb);

    // 3 GNN layers: aggregate, then fused GEMM1+GEMM2+LN+residual
    for (int l = 0; l < 3; l++) {
        k_agg<<<N_NODES / 4, 256, 0, stream>>>(xb, offs, csr, edge_emb, aggb);
        k_layer<<<N_NODES / 128, 512, 0, stream>>>(
            aggb, W1T + l * 32768, gnn_b1 + l * 256,
            W2T + l * 32768, gnn_b2 + l * 128,
            gnn_ln_g + l * 128, gnn_ln_b + l * 128, x, xb);
    }

    // fused gate
    k_gatef<<<N_NODES / 128, 512, 0, stream>>>(
        xb, gW1T, gate_b1, gate_ln_g, gate_ln_b, gate_W2, gate_b2, gate);

    // attention pooling
    k_pool<<<B_GRAPHS, 256, 0, stream>>>(x, gate, gpool);

    // residual blocks + head
    k_tail<<<B_GRAPHS, 128, 0, stream>>>(gpool,
        res_fc1_W, res_fc1_b, res_ln1_g, res_ln1_b,
        res_fc2_W, res_fc2_b, res_ln2_g, res_ln2_b,
        pred_W1, pred_b1, pred_W2, pred_b2, out);
}